// Round 4
// baseline (275.076 us; speedup 1.0000x reference)
//
#include <hip/hip_runtime.h>
#include <hip/hip_bf16.h>

typedef short s16x8 __attribute__((ext_vector_type(8)));
typedef short s16x4 __attribute__((ext_vector_type(4)));
typedef float f32x4 __attribute__((ext_vector_type(4)));

#define TB 8            // batch elements per group
#define NBG 4           // groups per block (sequential)
#define HALO 46         // gtile positions per batch (pos -2 .. 43)
#define GSTRIDE 2216    // shorts per batch in gtile (8*odd: bank-decorrelated)
#define USTRIDE 50      // floats per batch in u_s halo (50%32=18: banks decorrelated)
#define NT 3            // stage-2 N tiles (48 cols, >=37 zero-padded)
#define GT_SHORTS (TB * GSTRIDE)       // 17728 shorts = 35456 B
#define BL_SHORTS (NT * 8 * 64 * 8)    // 12288 shorts (W2 staging, aliased on gtile)

__device__ __forceinline__ unsigned short f2bf(float f) {
    unsigned int u = __float_as_uint(f);
    u += 0x7fff + ((u >> 16) & 1);   // RNE
    return (unsigned short)(u >> 16);
}

// packed f32x2 -> bf16x2 (v_cvt_pk_bf16_f32, RNE)
__device__ __forceinline__ unsigned int pk_bf16(float lo, float hi) {
    float2 f; f.x = lo; f.y = hi;
    __hip_bfloat162 h = __float22bfloat162_rn(f);
    union { __hip_bfloat162 b; unsigned int u; } c;
    c.b = h;
    return c.u;
}

__global__ __launch_bounds__(256, 3) void lorenz96_fused(
    const float* __restrict__ u,
    const float* __restrict__ coeff,
    const float* __restrict__ W1,
    const float* __restrict__ b1,
    const float* __restrict__ W2,
    const float* __restrict__ b2,
    const float* __restrict__ W3,
    const float* __restrict__ b3,
    float* __restrict__ out)
{
    // LDS: gtile 35456 (aliases W2 staging) + u_sbuf 3200 + out1_s 1280 = 39936 B
    __shared__ __align__(16) unsigned short gtile[GT_SHORTS];
    __shared__ __align__(16) float u_sbuf[2][TB * USTRIDE];   // u_s[b][k] = u[b][(k+36)%40]
    __shared__ float out1_s[TB * 40];

    unsigned short* B_lds = gtile;   // alias: consumed into regs before gtile is written

    const int t    = threadIdx.x;
    const int lane = t & 63;
    const int wave = t >> 6;
    const int quad = lane >> 4;
    const int l15  = lane & 15;

    const int b0_block = blockIdx.x * (TB * NBG);

    // ---------- init 0a: W2 staging, pre-swizzled to MFMA fragment order ----------
    // W2eff[o][k = tap*48 + c] = W2[o][c][tap]; lane holds [o = nt*16+l15][k = ks*32+quad*8+j]
    for (int g = t; g < NT * 8 * 64; g += 256) {
        int lg = g & 63;
        int ks = (g >> 6) & 7;
        int nt = g >> 9;
        int o  = nt * 16 + (lg & 15);
        int kb = ks * 32 + (lg >> 4) * 8;
        s16x8 pack = {0, 0, 0, 0, 0, 0, 0, 0};
        #pragma unroll
        for (int j = 0; j < 8; ++j) {
            int k = kb + j;
            if (k < 240 && o < 37) {
                int c = k % 48, tap = k / 48;
                pack[j] = (short)f2bf(W2[o * 240 + c * 5 + tap]);
            }
        }
        *(s16x8*)&B_lds[g * 8] = pack;
    }

    // ---------- init 0b: stage u halo for group 0 (coalesced) ----------
    for (int idx = t; idx < TB * USTRIDE; idx += 256) {
        int b = idx / USTRIDE, k = idx - b * USTRIDE;
        int gi = k + 36; gi -= (gi >= 40) ? 40 : 0; gi -= (gi >= 40) ? 40 : 0;
        u_sbuf[0][idx] = u[(size_t)(b0_block + b) * 40 + gi];
    }

    // ---------- init 0c: conv1 A-fragments (W1 + fused b1 at k=5) ----------
    // tiles: T0=ch0-15, T1=ch16-31, T2=ch32-47, T3 rows8-15=ch48-55, T4=ch56-71.
    // GLU in-lane: T1 rows8-15 x T3 rows8-15; T2 x T4 (same quad,reg).
    s16x8 aW1[5];
    {
        int chs[5];
        chs[0] = l15; chs[1] = 16 + l15; chs[2] = 32 + l15;
        chs[3] = (l15 >= 8) ? 40 + l15 : -1;
        chs[4] = 56 + l15;
        #pragma unroll
        for (int mt = 0; mt < 5; ++mt) {
            s16x8 a = {0, 0, 0, 0, 0, 0, 0, 0};
            int ch = chs[mt];
            if (quad == 0 && ch >= 0) {
                #pragma unroll
                for (int j = 0; j < 5; ++j) a[j] = (short)f2bf(W1[ch * 5 + j]);
                a[5] = (short)f2bf(b1[ch]);   // bias slot; B supplies 1.0 at k=5
            }
            aW1[mt] = a;
        }
    }

    // ---------- init 0d: epilogue constants ----------
    float w3v[NT][4], b2v[NT][4];
    #pragma unroll
    for (int nt = 0; nt < NT; ++nt)
        #pragma unroll
        for (int r = 0; r < 4; ++r) {
            int o = nt * 16 + quad * 4 + r;
            bool valid = (o < 37);
            w3v[nt][r] = valid ? W3[o] : 0.f;
            b2v[nt][r] = valid ? b2[o] : 0.f;
        }
    const float b3v = b3[0];
    float cf[18];
    #pragma unroll
    for (int i = 0; i < 18; ++i) cf[i] = coeff[i];

    __syncthreads();   // B_lds + u_sbuf[0] ready

    // stage-2 A-fragments (W2), register-resident for whole kernel
    s16x8 aW2[NT][8];
    #pragma unroll
    for (int nt = 0; nt < NT; ++nt)
        #pragma unroll
        for (int ks = 0; ks < 8; ++ks)
            aW2[nt][ks] = *(const s16x8*)&B_lds[((nt * 8 + ks) * 64 + lane) * 8];

    for (int grp = 0; grp < NBG; ++grp) {
        const int b0 = b0_block + grp * TB;
        const float* u_s = u_sbuf[grp & 1];

        __syncthreads();   // grp0: aW2 reads done (gtile alias); grp>0: prev phase-3 reads done

        // ---------- poly term for this wave's own output rows (same-wave LDS, no barrier) ----------
        {
            #pragma unroll
            for (int pass = 0; pass < 2; ++pass) {
                int i = pass ? 4 : quad;
                bool act = pass ? (quad == 0) : true;
                if (act) {
                    int m = (wave + 4 * i) * 16 + l15;
                    int p = m >> 3, b = m & 7;
                    const float* us = &u_s[b * USTRIDE + p];
                    float um2 = us[2], um1 = us[3], u0 = us[4], up1 = us[5], up2 = us[6];
                    float r = cf[0] + cf[1]*um2 + cf[2]*um1 + cf[3]*u0 + cf[4]*up1 + cf[5]*up2
                            + cf[6]*um2*um2 + cf[7]*um1*um1 + cf[8]*u0*u0 + cf[9]*up1*up1 + cf[10]*up2*up2
                            + cf[11]*um2*um1 + cf[12]*um1*u0 + cf[13]*u0*up1 + cf[14]*up1*up2
                            + cf[15]*um2*u0 + cf[16]*um1*up1 + cf[17]*u0*up2;
                    out1_s[m] = r;
                }
            }
        }

        // ---------- phase 2: conv1 via MFMA (taps straight from u_s halo) ----------
        #pragma unroll
        for (int i = 0; i < 6; ++i) {
            const int ct  = wave + 4 * i;              // 24 col-tiles (368 live cols)
            const int col = ct * 16 + l15;
            const int b = col & 7, h = col >> 3;
            const int hc = (h < HALO) ? h : 0;
            s16x8 bU = {0, 0, 0, 0, 0, 0, 0, 0};
            if (quad == 0) {
                const float* us = &u_s[b * USTRIDE + hc];   // taps u[(h-4+j)%40], j=0..4
                union { s16x8 v; unsigned int w[4]; } bu;
                bu.w[0] = pk_bf16(us[0], us[1]);
                bu.w[1] = pk_bf16(us[2], us[3]);
                bu.w[2] = pk_bf16(us[4], 1.0f);            // 1.0 -> bias slot k=5
                bu.w[3] = 0;
                bU = bu.v;
            }
            f32x4 a0 = {0.f,0.f,0.f,0.f}, a1 = a0, a2 = a0, a3 = a0, a4 = a0;
            a0 = __builtin_amdgcn_mfma_f32_16x16x32_bf16(aW1[0], bU, a0, 0, 0, 0);
            a1 = __builtin_amdgcn_mfma_f32_16x16x32_bf16(aW1[1], bU, a1, 0, 0, 0);
            a2 = __builtin_amdgcn_mfma_f32_16x16x32_bf16(aW1[2], bU, a2, 0, 0, 0);
            a3 = __builtin_amdgcn_mfma_f32_16x16x32_bf16(aW1[3], bU, a3, 0, 0, 0);
            a4 = __builtin_amdgcn_mfma_f32_16x16x32_bf16(aW1[4], bU, a4, 0, 0, 0);
            if (h < HALO) {
                float v0[4], v1[4], v2[4];
                #pragma unroll
                for (int r = 0; r < 4; ++r) {
                    v0[r] = fmaxf(a0[r], 0.f);
                    v1[r] = fmaxf(a1[r], 0.f);
                    if (quad >= 2) v1[r] *= fmaxf(a3[r], 0.f);          // ch24-31 gate
                    v2[r] = fmaxf(a2[r], 0.f) * fmaxf(a4[r], 0.f);      // ch32-47 gate
                }
                union { s16x4 v; unsigned int w[2]; } w0, w1, w2;
                w0.w[0] = pk_bf16(v0[0], v0[1]); w0.w[1] = pk_bf16(v0[2], v0[3]);
                w1.w[0] = pk_bf16(v1[0], v1[1]); w1.w[1] = pk_bf16(v1[2], v1[3]);
                w2.w[0] = pk_bf16(v2[0], v2[1]); w2.w[1] = pk_bf16(v2[2], v2[3]);
                unsigned short* gp = &gtile[b * GSTRIDE + h * 48 + quad * 4];
                *(s16x4*)(gp)      = w0.v;
                *(s16x4*)(gp + 16) = w1.v;
                *(s16x4*)(gp + 32) = w2.v;
            }
        }

        // ---------- pre-stage next group's u halo (writes other buffer; ordered by barrier below) ----------
        if (grp + 1 < NBG) {
            for (int idx = t; idx < TB * USTRIDE; idx += 256) {
                int b = idx / USTRIDE, k = idx - b * USTRIDE;
                int gi = k + 36; gi -= (gi >= 40) ? 40 : 0; gi -= (gi >= 40) ? 40 : 0;
                u_sbuf[(grp + 1) & 1][idx] = u[(size_t)(b0 + TB + b) * 40 + gi];
            }
        }

        __syncthreads();   // gtile ready (and next u halo staged)

        // ---------- phase 3: stage-2 GEMM (A=W2 regs, B=G from LDS) + fused epilogue ----------
        #pragma unroll
        for (int i = 0; i < 5; ++i) {
            const int mt = wave + 4 * i;               // 20 M-tiles (320 G-rows)
            const int m  = mt * 16 + l15;
            const int p  = m >> 3, b = m & 7;
            const unsigned short* gbase = &gtile[b * GSTRIDE + p * 48 + quad * 8];
            s16x8 bg[8];
            #pragma unroll
            for (int ks = 0; ks < 8; ++ks) bg[ks] = *(const s16x8*)(gbase + ks * 32);
            f32x4 c0 = {0.f,0.f,0.f,0.f}, c1 = c0, c2 = c0;
            #pragma unroll
            for (int ks = 0; ks < 8; ++ks) {
                c0 = __builtin_amdgcn_mfma_f32_16x16x32_bf16(aW2[0][ks], bg[ks], c0, 0, 0, 0);
                c1 = __builtin_amdgcn_mfma_f32_16x16x32_bf16(aW2[1][ks], bg[ks], c1, 0, 0, 0);
                c2 = __builtin_amdgcn_mfma_f32_16x16x32_bf16(aW2[2][ks], bg[ks], c2, 0, 0, 0);
            }
            float s = 0.f;
            #pragma unroll
            for (int r = 0; r < 4; ++r) {
                s += fmaxf(c0[r] + b2v[0][r], 0.f) * w3v[0][r];
                s += fmaxf(c1[r] + b2v[1][r], 0.f) * w3v[1][r];
                s += fmaxf(c2[r] + b2v[2][r], 0.f) * w3v[2][r];
            }
            s += __shfl_xor(s, 16, 64);
            s += __shfl_xor(s, 32, 64);
            if (lane < 16) {
                int mo = mt * 16 + lane;
                out[(size_t)(b0 + (mo & 7)) * 40 + (mo >> 3)] = s + b3v + out1_s[mo];
            }
        }
    }
}

extern "C" void kernel_launch(void* const* d_in, const int* in_sizes, int n_in,
                              void* d_out, int out_size, void* d_ws, size_t ws_size,
                              hipStream_t stream) {
    // inputs: 0=t(unused), 1=u, 2=coeff, 3=W1, 4=b1, 5=W2, 6=b2, 7=W3, 8=b3
    const float* u     = (const float*)d_in[1];
    const float* coeff = (const float*)d_in[2];
    const float* W1    = (const float*)d_in[3];
    const float* b1    = (const float*)d_in[4];
    const float* W2    = (const float*)d_in[5];
    const float* b2    = (const float*)d_in[6];
    const float* W3    = (const float*)d_in[7];
    const float* b3    = (const float*)d_in[8];
    float* out = (float*)d_out;

    const int n_batch = in_sizes[1] / 40;            // 65536
    const int grid = n_batch / (TB * NBG);           // 2048 blocks
    lorenz96_fused<<<grid, 256, 0, stream>>>(u, coeff, W1, b1, W2, b2, W3, b3, out);
}

// Round 5
// 214.946 us; speedup vs baseline: 1.2797x; 1.2797x over previous
//
#include <hip/hip_runtime.h>
#include <hip/hip_bf16.h>

typedef short s16x8 __attribute__((ext_vector_type(8)));
typedef short s16x4 __attribute__((ext_vector_type(4)));
typedef float f32x4 __attribute__((ext_vector_type(4)));

#define TB 8            // batch elements per group
#define NBG 4           // groups per block (sequential)
#define HALO 46         // gtile positions per batch (pos -2 .. 43)
#define GSTRIDE 2216    // shorts per batch in gtile (8*odd: bank-decorrelated)
#define USTRIDE 50      // floats per batch in u_s halo
#define NT 3            // stage-2 N tiles (48 cols, >=37 zero-padded)
#define GT_SHORTS (TB * GSTRIDE)       // 17728 shorts = 35456 B

__device__ __forceinline__ unsigned short f2bf(float f) {
    unsigned int u = __float_as_uint(f);
    u += 0x7fff + ((u >> 16) & 1);   // RNE
    return (unsigned short)(u >> 16);
}

// packed f32x2 -> bf16x2 (v_cvt_pk_bf16_f32, RNE)
__device__ __forceinline__ unsigned int pk_bf16(float lo, float hi) {
    float2 f; f.x = lo; f.y = hi;
    __hip_bfloat162 h = __float22bfloat162_rn(f);
    union { __hip_bfloat162 b; unsigned int u; } c;
    c.b = h;
    return c.u;
}

__global__ __launch_bounds__(256, 3) void lorenz96_fused(
    const float* __restrict__ u,
    const float* __restrict__ coeff,
    const float* __restrict__ W1,
    const float* __restrict__ b1,
    const float* __restrict__ W2,
    const float* __restrict__ b2,
    const float* __restrict__ W3,
    const float* __restrict__ b3,
    float* __restrict__ out)
{
    // LDS: gtile 35456 (aliases W2 staging) + u_sbuf 3200 + out1_s 1280 + part 3840 = 43776 B
    // -> 3 blocks/CU (LDS-bound); reg budget 512/3 ~ 170, kernel needs ~135 -> no spill
    __shared__ __align__(16) unsigned short gtile[GT_SHORTS];
    __shared__ __align__(16) float u_sbuf[2][TB * USTRIDE];   // u_s[b][k] = u[b][(k+36)%40]
    __shared__ float out1_s[TB * 40];
    __shared__ float part[3][TB * 40];                        // per-nt partial W3-dot sums

    unsigned short* B_lds = gtile;   // alias: consumed into regs before gtile is written

    const int t    = threadIdx.x;
    const int lane = t & 63;
    const int wave = t >> 6;
    const int quad = lane >> 4;
    const int l15  = lane & 15;

    const int b0_block = blockIdx.x * (TB * NBG);

    // ---------- init 0a: W2 staging, pre-swizzled to MFMA fragment order ----------
    // W2eff[o][k = tap*48 + c] = W2[o][c][tap]; lane holds [o = nt*16+l15][k = ks*32+quad*8+j]
    for (int g = t; g < NT * 8 * 64; g += 256) {
        int lg = g & 63;
        int ks = (g >> 6) & 7;
        int nt = g >> 9;
        int o  = nt * 16 + (lg & 15);
        int kb = ks * 32 + (lg >> 4) * 8;
        s16x8 pack = {0, 0, 0, 0, 0, 0, 0, 0};
        #pragma unroll
        for (int j = 0; j < 8; ++j) {
            int k = kb + j;
            if (k < 240 && o < 37) {
                int c = k % 48, tap = k / 48;
                pack[j] = (short)f2bf(W2[o * 240 + c * 5 + tap]);
            }
        }
        *(s16x8*)&B_lds[g * 8] = pack;
    }

    // ---------- init 0b: stage u halo for group 0 (coalesced) ----------
    for (int idx = t; idx < TB * USTRIDE; idx += 256) {
        int b = idx / USTRIDE, k = idx - b * USTRIDE;
        int gi = k + 36; gi -= (gi >= 40) ? 40 : 0; gi -= (gi >= 40) ? 40 : 0;
        u_sbuf[0][idx] = u[(size_t)(b0_block + b) * 40 + gi];
    }

    // ---------- init 0c: conv1 A-fragments (W1 + fused b1 at k=5) ----------
    // tiles: T0=ch0-15, T1=ch16-31, T2=ch32-47, T3 rows8-15=ch48-55, T4=ch56-71.
    // GLU in-lane: T1 rows8-15 x T3 rows8-15; T2 x T4 (same quad,reg).
    s16x8 aW1[5];
    {
        int chs[5];
        chs[0] = l15; chs[1] = 16 + l15; chs[2] = 32 + l15;
        chs[3] = (l15 >= 8) ? 40 + l15 : -1;
        chs[4] = 56 + l15;
        #pragma unroll
        for (int mt = 0; mt < 5; ++mt) {
            s16x8 a = {0, 0, 0, 0, 0, 0, 0, 0};
            int ch = chs[mt];
            if (quad == 0 && ch >= 0) {
                #pragma unroll
                for (int j = 0; j < 5; ++j) a[j] = (short)f2bf(W1[ch * 5 + j]);
                a[5] = (short)f2bf(b1[ch]);   // bias slot; B supplies 1.0 at k=5
            }
            aW1[mt] = a;
        }
    }

    // ---------- init 0d: epilogue constants (only waves 0-2: nt = wave) ----------
    float w3v[4], b2v[4];
    if (wave < 3) {
        #pragma unroll
        for (int r = 0; r < 4; ++r) {
            int o = wave * 16 + quad * 4 + r;
            bool valid = (o < 37);
            w3v[r] = valid ? W3[o] : 0.f;
            b2v[r] = valid ? b2[o] : 0.f;
        }
    }
    const float b3v = b3[0];
    float cf[18];
    #pragma unroll
    for (int i = 0; i < 18; ++i) cf[i] = coeff[i];

    __syncthreads();   // B_lds + u_sbuf[0] ready

    // stage-2 A-fragments: wave w holds only nt=w (32 regs)
    s16x8 aW2w[8];
    if (wave < 3) {
        #pragma unroll
        for (int ks = 0; ks < 8; ++ks)
            aW2w[ks] = *(const s16x8*)&B_lds[((wave * 8 + ks) * 64 + lane) * 8];
    }

    for (int grp = 0; grp < NBG; ++grp) {
        const int b0 = b0_block + grp * TB;
        const float* u_s = u_sbuf[grp & 1];

        __syncthreads();   // barrier A: prev combine reads done; grp0: aW2 reads done (gtile alias)

        // ---------- poly term, distributed (each quad owns one M-tile's rows) ----------
        {
            #pragma unroll
            for (int pass = 0; pass < 2; ++pass) {
                int i = pass ? 4 : quad;
                bool act = pass ? (quad == 0) : true;
                if (act) {
                    int m = (wave + 4 * i) * 16 + l15;
                    int p = m >> 3, b = m & 7;
                    const float* us = &u_s[b * USTRIDE + p];
                    float um2 = us[2], um1 = us[3], u0 = us[4], up1 = us[5], up2 = us[6];
                    float r = cf[0] + cf[1]*um2 + cf[2]*um1 + cf[3]*u0 + cf[4]*up1 + cf[5]*up2
                            + cf[6]*um2*um2 + cf[7]*um1*um1 + cf[8]*u0*u0 + cf[9]*up1*up1 + cf[10]*up2*up2
                            + cf[11]*um2*um1 + cf[12]*um1*u0 + cf[13]*u0*up1 + cf[14]*up1*up2
                            + cf[15]*um2*u0 + cf[16]*um1*up1 + cf[17]*u0*up2;
                    out1_s[m] = r;
                }
            }
        }

        // ---------- phase 2: conv1 via MFMA (taps straight from u_s halo) ----------
        #pragma unroll
        for (int i = 0; i < 6; ++i) {
            const int ct  = wave + 4 * i;              // 24 col-tiles (368 live cols)
            const int col = ct * 16 + l15;
            const int b = col & 7, h = col >> 3;
            const int hc = (h < HALO) ? h : 0;
            s16x8 bU = {0, 0, 0, 0, 0, 0, 0, 0};
            if (quad == 0) {
                const float* us = &u_s[b * USTRIDE + hc];   // taps u[(h-4+j)%40], j=0..4
                union { s16x8 v; unsigned int w[4]; } bu;
                bu.w[0] = pk_bf16(us[0], us[1]);
                bu.w[1] = pk_bf16(us[2], us[3]);
                bu.w[2] = pk_bf16(us[4], 1.0f);            // 1.0 -> bias slot k=5
                bu.w[3] = 0;
                bU = bu.v;
            }
            f32x4 a0 = {0.f,0.f,0.f,0.f}, a1 = a0, a2 = a0, a3 = a0, a4 = a0;
            a0 = __builtin_amdgcn_mfma_f32_16x16x32_bf16(aW1[0], bU, a0, 0, 0, 0);
            a1 = __builtin_amdgcn_mfma_f32_16x16x32_bf16(aW1[1], bU, a1, 0, 0, 0);
            a2 = __builtin_amdgcn_mfma_f32_16x16x32_bf16(aW1[2], bU, a2, 0, 0, 0);
            a3 = __builtin_amdgcn_mfma_f32_16x16x32_bf16(aW1[3], bU, a3, 0, 0, 0);
            a4 = __builtin_amdgcn_mfma_f32_16x16x32_bf16(aW1[4], bU, a4, 0, 0, 0);
            if (h < HALO) {
                float v0[4], v1[4], v2[4];
                #pragma unroll
                for (int r = 0; r < 4; ++r) {
                    v0[r] = fmaxf(a0[r], 0.f);
                    v1[r] = fmaxf(a1[r], 0.f);
                    if (quad >= 2) v1[r] *= fmaxf(a3[r], 0.f);          // ch24-31 gate
                    v2[r] = fmaxf(a2[r], 0.f) * fmaxf(a4[r], 0.f);      // ch32-47 gate
                }
                union { s16x4 v; unsigned int w[2]; } w0, w1, w2;
                w0.w[0] = pk_bf16(v0[0], v0[1]); w0.w[1] = pk_bf16(v0[2], v0[3]);
                w1.w[0] = pk_bf16(v1[0], v1[1]); w1.w[1] = pk_bf16(v1[2], v1[3]);
                w2.w[0] = pk_bf16(v2[0], v2[1]); w2.w[1] = pk_bf16(v2[2], v2[3]);
                unsigned short* gp = &gtile[b * GSTRIDE + h * 48 + quad * 4];
                *(s16x4*)(gp)      = w0.v;
                *(s16x4*)(gp + 16) = w1.v;
                *(s16x4*)(gp + 32) = w2.v;
            }
        }

        // ---------- pre-stage next group's u halo ----------
        if (grp + 1 < NBG) {
            for (int idx = t; idx < TB * USTRIDE; idx += 256) {
                int b = idx / USTRIDE, k = idx - b * USTRIDE;
                int gi = k + 36; gi -= (gi >= 40) ? 40 : 0; gi -= (gi >= 40) ? 40 : 0;
                u_sbuf[(grp + 1) & 1][idx] = u[(size_t)(b0 + TB + b) * 40 + gi];
            }
        }

        __syncthreads();   // barrier B: gtile + out1_s ready

        // ---------- phase 3: wave w computes nt=w for ALL 20 M-tiles ----------
        if (wave < 3) {
            for (int mt = 0; mt < 20; ++mt) {
                const int m = mt * 16 + l15;
                const int p = m >> 3, b = m & 7;
                const unsigned short* gbase = &gtile[b * GSTRIDE + p * 48 + quad * 8];
                s16x8 bg[8];
                #pragma unroll
                for (int ks = 0; ks < 8; ++ks) bg[ks] = *(const s16x8*)(gbase + ks * 32);
                f32x4 c = {0.f, 0.f, 0.f, 0.f};
                #pragma unroll
                for (int ks = 0; ks < 8; ++ks)
                    c = __builtin_amdgcn_mfma_f32_16x16x32_bf16(aW2w[ks], bg[ks], c, 0, 0, 0);
                float s = 0.f;
                #pragma unroll
                for (int r = 0; r < 4; ++r)
                    s += fmaxf(c[r] + b2v[r], 0.f) * w3v[r];
                s += __shfl_xor(s, 16, 64);      // sum the 4 quads (16 channels of this nt)
                s += __shfl_xor(s, 32, 64);
                if (lane < 16) part[wave][mt * 16 + lane] = s;
            }
        }

        __syncthreads();   // barrier C: partials ready

        // ---------- combine: out = part0+part1+part2 + poly + b3 ----------
        for (int m = t; m < TB * 40; m += 256) {
            float s = part[0][m] + part[1][m] + part[2][m] + out1_s[m] + b3v;
            out[(size_t)(b0 + (m & 7)) * 40 + (m >> 3)] = s;
        }
    }
}

extern "C" void kernel_launch(void* const* d_in, const int* in_sizes, int n_in,
                              void* d_out, int out_size, void* d_ws, size_t ws_size,
                              hipStream_t stream) {
    // inputs: 0=t(unused), 1=u, 2=coeff, 3=W1, 4=b1, 5=W2, 6=b2, 7=W3, 8=b3
    const float* u     = (const float*)d_in[1];
    const float* coeff = (const float*)d_in[2];
    const float* W1    = (const float*)d_in[3];
    const float* b1    = (const float*)d_in[4];
    const float* W2    = (const float*)d_in[5];
    const float* b2    = (const float*)d_in[6];
    const float* W3    = (const float*)d_in[7];
    const float* b3    = (const float*)d_in[8];
    float* out = (float*)d_out;

    const int n_batch = in_sizes[1] / 40;            // 65536
    const int grid = n_batch / (TB * NBG);           // 2048 blocks
    lorenz96_fused<<<grid, 256, 0, stream>>>(u, coeff, W1, b1, W2, b2, W3, b3, out);
}

// Round 6
// 211.114 us; speedup vs baseline: 1.3030x; 1.0182x over previous
//
#include <hip/hip_runtime.h>
#include <hip/hip_bf16.h>

typedef short s16x8 __attribute__((ext_vector_type(8)));
typedef short s16x4 __attribute__((ext_vector_type(4)));
typedef float f32x4 __attribute__((ext_vector_type(4)));

#define TB 8            // batch elements per group
#define NBG 4           // groups per block (sequential)
#define HALO 46         // gtile positions per batch (pos -2 .. 43)
#define GSTRIDE 2216    // shorts per batch in gtile (8*odd: bank-decorrelated)
#define USTRIDE 50      // floats per batch in u_s halo
#define NT 3            // stage-2 N tiles (48 cols, >=37 zero-padded)
#define GT_SHORTS (TB * GSTRIDE)       // 17728 shorts = 35456 B

__device__ __forceinline__ unsigned short f2bf(float f) {
    unsigned int u = __float_as_uint(f);
    u += 0x7fff + ((u >> 16) & 1);   // RNE
    return (unsigned short)(u >> 16);
}

// packed f32x2 -> bf16x2 (v_cvt_pk_bf16_f32, RNE)
__device__ __forceinline__ unsigned int pk_bf16(float lo, float hi) {
    float2 f; f.x = lo; f.y = hi;
    __hip_bfloat162 h = __float22bfloat162_rn(f);
    union { __hip_bfloat162 b; unsigned int u; } c;
    c.b = h;
    return c.u;
}

__global__ __launch_bounds__(256, 2) void lorenz96_fused(
    const float* __restrict__ u,
    const float* __restrict__ coeff,
    const float* __restrict__ W1,
    const float* __restrict__ b1,
    const float* __restrict__ W2,
    const float* __restrict__ b2,
    const float* __restrict__ W3,
    const float* __restrict__ b3,
    float* __restrict__ out)
{
    // LDS: gtile 35456 (aliases W2 staging) + u_sbuf 3200 + out1_s 1280 = 39936 B
    // (256,2): reg cap 256 -- aW2(96)+aW1(20)+bg(32)+acc(12)+consts fits, NO spill (R4 lesson)
    __shared__ __align__(16) unsigned short gtile[GT_SHORTS];
    __shared__ __align__(16) float u_sbuf[2][TB * USTRIDE];   // u_s[b][k] = u[b][(k+36)%40]
    __shared__ float out1_s[TB * 40];

    unsigned short* B_lds = gtile;   // alias: consumed into regs before gtile is written

    const int t    = threadIdx.x;
    const int lane = t & 63;
    const int wave = t >> 6;
    const int quad = lane >> 4;
    const int l15  = lane & 15;

    const int b0_block = blockIdx.x * (TB * NBG);

    // ---------- init 0a: W2 staging, pre-swizzled to MFMA fragment order ----------
    // W2eff[o][k = tap*48 + c] = W2[o][c][tap]; lane holds [o = nt*16+l15][k = ks*32+quad*8+j]
    for (int g = t; g < NT * 8 * 64; g += 256) {
        int lg = g & 63;
        int ks = (g >> 6) & 7;
        int nt = g >> 9;
        int o  = nt * 16 + (lg & 15);
        int kb = ks * 32 + (lg >> 4) * 8;
        s16x8 pack = {0, 0, 0, 0, 0, 0, 0, 0};
        #pragma unroll
        for (int j = 0; j < 8; ++j) {
            int k = kb + j;
            if (k < 240 && o < 37) {
                int c = k % 48, tap = k / 48;
                pack[j] = (short)f2bf(W2[o * 240 + c * 5 + tap]);
            }
        }
        *(s16x8*)&B_lds[g * 8] = pack;
    }

    // ---------- init 0b: stage u halo for group 0 (coalesced) ----------
    for (int idx = t; idx < TB * USTRIDE; idx += 256) {
        int b = idx / USTRIDE, k = idx - b * USTRIDE;
        int gi = k + 36; gi -= (gi >= 40) ? 40 : 0; gi -= (gi >= 40) ? 40 : 0;
        u_sbuf[0][idx] = u[(size_t)(b0_block + b) * 40 + gi];
    }

    // ---------- init 0c: conv1 A-fragments (W1 + fused b1 at k=5) ----------
    // tiles: T0=ch0-15, T1=ch16-31, T2=ch32-47, T3 rows8-15=ch48-55, T4=ch56-71.
    // GLU in-lane: T1 rows8-15 x T3 rows8-15; T2 x T4 (same quad,reg).
    s16x8 aW1[5];
    {
        int chs[5];
        chs[0] = l15; chs[1] = 16 + l15; chs[2] = 32 + l15;
        chs[3] = (l15 >= 8) ? 40 + l15 : -1;
        chs[4] = 56 + l15;
        #pragma unroll
        for (int mt = 0; mt < 5; ++mt) {
            s16x8 a = {0, 0, 0, 0, 0, 0, 0, 0};
            int ch = chs[mt];
            if (quad == 0 && ch >= 0) {
                #pragma unroll
                for (int j = 0; j < 5; ++j) a[j] = (short)f2bf(W1[ch * 5 + j]);
                a[5] = (short)f2bf(b1[ch]);   // bias slot; B supplies 1.0 at k=5
            }
            aW1[mt] = a;
        }
    }

    // ---------- init 0d: epilogue constants ----------
    float w3v[NT][4], b2v[NT][4];
    #pragma unroll
    for (int nt = 0; nt < NT; ++nt)
        #pragma unroll
        for (int r = 0; r < 4; ++r) {
            int o = nt * 16 + quad * 4 + r;
            bool valid = (o < 37);
            w3v[nt][r] = valid ? W3[o] : 0.f;
            b2v[nt][r] = valid ? b2[o] : 0.f;
        }
    const float b3v = b3[0];
    float cf[18];
    #pragma unroll
    for (int i = 0; i < 18; ++i) cf[i] = coeff[i];

    __syncthreads();   // B_lds + u_sbuf[0] ready

    // stage-2 A-fragments (W2), all 3 N-tiles in every wave -> 3 independent MFMA chains
    s16x8 aW2[NT][8];
    #pragma unroll
    for (int nt = 0; nt < NT; ++nt)
        #pragma unroll
        for (int ks = 0; ks < 8; ++ks)
            aW2[nt][ks] = *(const s16x8*)&B_lds[((nt * 8 + ks) * 64 + lane) * 8];

    for (int grp = 0; grp < NBG; ++grp) {
        const int b0 = b0_block + grp * TB;
        const float* u_s = u_sbuf[grp & 1];

        __syncthreads();   // barrier A: prev phase-3 reads done; grp0: aW2 reads done (gtile alias)

        // ---------- poly term, distributed (wave's own output rows; done before barrier B) ----------
        {
            #pragma unroll
            for (int pass = 0; pass < 2; ++pass) {
                int i = pass ? 4 : quad;
                bool act = pass ? (quad == 0) : true;
                if (act) {
                    int m = (wave + 4 * i) * 16 + l15;
                    int p = m >> 3, b = m & 7;
                    const float* us = &u_s[b * USTRIDE + p];
                    float um2 = us[2], um1 = us[3], u0 = us[4], up1 = us[5], up2 = us[6];
                    float r = cf[0] + cf[1]*um2 + cf[2]*um1 + cf[3]*u0 + cf[4]*up1 + cf[5]*up2
                            + cf[6]*um2*um2 + cf[7]*um1*um1 + cf[8]*u0*u0 + cf[9]*up1*up1 + cf[10]*up2*up2
                            + cf[11]*um2*um1 + cf[12]*um1*u0 + cf[13]*u0*up1 + cf[14]*up1*up2
                            + cf[15]*um2*u0 + cf[16]*um1*up1 + cf[17]*u0*up2;
                    out1_s[m] = r;
                }
            }
        }

        // ---------- phase 2: conv1 via MFMA (taps straight from u_s halo) ----------
        #pragma unroll
        for (int i = 0; i < 6; ++i) {
            const int ct  = wave + 4 * i;              // 24 col-tiles (368 live cols)
            const int col = ct * 16 + l15;
            const int b = col & 7, h = col >> 3;
            const int hc = (h < HALO) ? h : 0;
            s16x8 bU = {0, 0, 0, 0, 0, 0, 0, 0};
            if (quad == 0) {
                const float* us = &u_s[b * USTRIDE + hc];   // taps u[(h-4+j)%40], j=0..4
                union { s16x8 v; unsigned int w[4]; } bu;
                bu.w[0] = pk_bf16(us[0], us[1]);
                bu.w[1] = pk_bf16(us[2], us[3]);
                bu.w[2] = pk_bf16(us[4], 1.0f);            // 1.0 -> bias slot k=5
                bu.w[3] = 0;
                bU = bu.v;
            }
            f32x4 a0 = {0.f,0.f,0.f,0.f}, a1 = a0, a2 = a0, a3 = a0, a4 = a0;
            a0 = __builtin_amdgcn_mfma_f32_16x16x32_bf16(aW1[0], bU, a0, 0, 0, 0);
            a1 = __builtin_amdgcn_mfma_f32_16x16x32_bf16(aW1[1], bU, a1, 0, 0, 0);
            a2 = __builtin_amdgcn_mfma_f32_16x16x32_bf16(aW1[2], bU, a2, 0, 0, 0);
            a3 = __builtin_amdgcn_mfma_f32_16x16x32_bf16(aW1[3], bU, a3, 0, 0, 0);
            a4 = __builtin_amdgcn_mfma_f32_16x16x32_bf16(aW1[4], bU, a4, 0, 0, 0);
            if (h < HALO) {
                float v0[4], v1[4], v2[4];
                #pragma unroll
                for (int r = 0; r < 4; ++r) {
                    v0[r] = fmaxf(a0[r], 0.f);
                    v1[r] = fmaxf(a1[r], 0.f);
                    if (quad >= 2) v1[r] *= fmaxf(a3[r], 0.f);          // ch24-31 gate
                    v2[r] = fmaxf(a2[r], 0.f) * fmaxf(a4[r], 0.f);      // ch32-47 gate
                }
                union { s16x4 v; unsigned int w[2]; } w0, w1, w2;
                w0.w[0] = pk_bf16(v0[0], v0[1]); w0.w[1] = pk_bf16(v0[2], v0[3]);
                w1.w[0] = pk_bf16(v1[0], v1[1]); w1.w[1] = pk_bf16(v1[2], v1[3]);
                w2.w[0] = pk_bf16(v2[0], v2[1]); w2.w[1] = pk_bf16(v2[2], v2[3]);
                unsigned short* gp = &gtile[b * GSTRIDE + h * 48 + quad * 4];
                *(s16x4*)(gp)      = w0.v;
                *(s16x4*)(gp + 16) = w1.v;
                *(s16x4*)(gp + 32) = w2.v;
            }
        }

        // ---------- pre-stage next group's u halo (other buffer; ordered by barrier B) ----------
        if (grp + 1 < NBG) {
            for (int idx = t; idx < TB * USTRIDE; idx += 256) {
                int b = idx / USTRIDE, k = idx - b * USTRIDE;
                int gi = k + 36; gi -= (gi >= 40) ? 40 : 0; gi -= (gi >= 40) ? 40 : 0;
                u_sbuf[(grp + 1) & 1][idx] = u[(size_t)(b0 + TB + b) * 40 + gi];
            }
        }

        __syncthreads();   // barrier B: gtile + out1_s ready

        // ---------- phase 3: each wave: 5 M-tiles x all 3 N-tiles (3 indep chains, shared bg) ----------
        #pragma unroll
        for (int i = 0; i < 5; ++i) {
            const int mt = wave + 4 * i;               // 20 M-tiles (320 G-rows)
            const int m  = mt * 16 + l15;
            const int p  = m >> 3, b = m & 7;
            const unsigned short* gbase = &gtile[b * GSTRIDE + p * 48 + quad * 8];
            s16x8 bg[8];
            #pragma unroll
            for (int ks = 0; ks < 8; ++ks) bg[ks] = *(const s16x8*)(gbase + ks * 32);
            f32x4 c0 = {0.f,0.f,0.f,0.f}, c1 = c0, c2 = c0;
            #pragma unroll
            for (int ks = 0; ks < 8; ++ks) {
                c0 = __builtin_amdgcn_mfma_f32_16x16x32_bf16(aW2[0][ks], bg[ks], c0, 0, 0, 0);
                c1 = __builtin_amdgcn_mfma_f32_16x16x32_bf16(aW2[1][ks], bg[ks], c1, 0, 0, 0);
                c2 = __builtin_amdgcn_mfma_f32_16x16x32_bf16(aW2[2][ks], bg[ks], c2, 0, 0, 0);
            }
            // epilogue: sum over output channels o (C rows) of relu(h2+b2)*W3[o]
            float s = 0.f;
            #pragma unroll
            for (int r = 0; r < 4; ++r) {
                s += fmaxf(c0[r] + b2v[0][r], 0.f) * w3v[0][r];
                s += fmaxf(c1[r] + b2v[1][r], 0.f) * w3v[1][r];
                s += fmaxf(c2[r] + b2v[2][r], 0.f) * w3v[2][r];
            }
            s += __shfl_xor(s, 16, 64);                // sum the 4 quads
            s += __shfl_xor(s, 32, 64);
            if (lane < 16) {
                int mo = mt * 16 + lane;
                out[(size_t)(b0 + (mo & 7)) * 40 + (mo >> 3)] = s + b3v + out1_s[mo];
            }
        }
    }
}

extern "C" void kernel_launch(void* const* d_in, const int* in_sizes, int n_in,
                              void* d_out, int out_size, void* d_ws, size_t ws_size,
                              hipStream_t stream) {
    // inputs: 0=t(unused), 1=u, 2=coeff, 3=W1, 4=b1, 5=W2, 6=b2, 7=W3, 8=b3
    const float* u     = (const float*)d_in[1];
    const float* coeff = (const float*)d_in[2];
    const float* W1    = (const float*)d_in[3];
    const float* b1    = (const float*)d_in[4];
    const float* W2    = (const float*)d_in[5];
    const float* b2    = (const float*)d_in[6];
    const float* W3    = (const float*)d_in[7];
    const float* b3    = (const float*)d_in[8];
    float* out = (float*)d_out;

    const int n_batch = in_sizes[1] / 40;            // 65536
    const int grid = n_batch / (TB * NBG);           // 2048 blocks
    lorenz96_fused<<<grid, 256, 0, stream>>>(u, coeff, W1, b1, W2, b2, W3, b3, out);
}

// Round 7
// 194.162 us; speedup vs baseline: 1.4167x; 1.0873x over previous
//
#include <hip/hip_runtime.h>
#include <hip/hip_bf16.h>

typedef short s16x8 __attribute__((ext_vector_type(8)));
typedef short s16x4 __attribute__((ext_vector_type(4)));
typedef float f32x4 __attribute__((ext_vector_type(4)));

#define TB 8            // batch elements per group
#define NBG 8           // groups per block (sequential)
#define HALO 46         // gtile positions per batch (pos -2 .. 43)
#define GSTRIDE 2216    // shorts per batch in gtile (8*odd: bank-decorrelated, conflict-free P3 reads)
#define USTRIDE 50      // floats per batch in u_s halo
#define NT 3            // stage-2 N tiles (48 cols, >=37 zero-padded; k=240 = b2 row)
#define GT_SHORTS (TB * GSTRIDE)       // 17728 shorts = 35456 B per buffer

__device__ __forceinline__ unsigned short f2bf(float f) {
    unsigned int u = __float_as_uint(f);
    u += 0x7fff + ((u >> 16) & 1);   // RNE
    return (unsigned short)(u >> 16);
}

// packed f32x2 -> bf16x2 (v_cvt_pk_bf16_f32, RNE)
__device__ __forceinline__ unsigned int pk_bf16(float lo, float hi) {
    float2 f; f.x = lo; f.y = hi;
    __hip_bfloat162 h = __float22bfloat162_rn(f);
    union { __hip_bfloat162 b; unsigned int u; } c;
    c.b = h;
    return c.u;
}

__global__ __launch_bounds__(256, 2) void lorenz96_fused(
    const float* __restrict__ u,
    const float* __restrict__ coeff,
    const float* __restrict__ W1,
    const float* __restrict__ b1,
    const float* __restrict__ W2,
    const float* __restrict__ b2,
    const float* __restrict__ W3,
    const float* __restrict__ b3,
    float* __restrict__ out)
{
    // LDS: gtile 2x35456 (buf0 aliases W2 staging) + u_sbuf 3200 + out1_sb 2560 = 76672 B
    // -> 2 blocks/CU (76.7 <= 80 KB). Ping-pong: P3(g) and P2(g+1) share one barrier window.
    __shared__ __align__(16) unsigned short gtile[2][GT_SHORTS];
    __shared__ __align__(16) float u_sbuf[2][TB * USTRIDE];   // u_s[b][k] = u[b][(k+36)%40]
    __shared__ float out1_sb[2][TB * 40];

    unsigned short* B_lds = &gtile[0][0];   // alias: consumed into regs before gtile[0] is written

    const int t    = threadIdx.x;
    const int lane = t & 63;
    const int wave = t >> 6;
    const int quad = lane >> 4;
    const int l15  = lane & 15;

    const int b0_block = blockIdx.x * (TB * NBG);

    // ---------- init 0a: W2 staging, pre-swizzled; k=240 carries b2 (bias row, B supplies 1.0) ----------
    // W2eff[o][k = tap*48 + c] = W2[o][c][tap]; lane holds [o = nt*16+l15][k = ks*32+quad*8+j]
    for (int g = t; g < NT * 8 * 64; g += 256) {
        int lg = g & 63;
        int ks = (g >> 6) & 7;
        int nt = g >> 9;
        int o  = nt * 16 + (lg & 15);
        int kb = ks * 32 + (lg >> 4) * 8;
        s16x8 pack = {0, 0, 0, 0, 0, 0, 0, 0};
        #pragma unroll
        for (int j = 0; j < 8; ++j) {
            int k = kb + j;
            if (o < 37) {
                if (k < 240) {
                    int c = k % 48, tap = k / 48;
                    pack[j] = (short)f2bf(W2[o * 240 + c * 5 + tap]);
                } else if (k == 240) {
                    pack[j] = (short)f2bf(b2[o]);
                }
            }
        }
        *(s16x8*)&B_lds[g * 8] = pack;
    }

    // ---------- init 0b: conv1 A-fragments (W1 + fused b1 at k=5) ----------
    // tiles: T0=ch0-15, T1=ch16-31, T2=ch32-47, T3 rows8-15=ch48-55, T4=ch56-71.
    // GLU in-lane: T1 rows8-15 x T3 rows8-15; T2 x T4 (same quad,reg).
    s16x8 aW1[5];
    {
        int chs[5];
        chs[0] = l15; chs[1] = 16 + l15; chs[2] = 32 + l15;
        chs[3] = (l15 >= 8) ? 40 + l15 : -1;
        chs[4] = 56 + l15;
        #pragma unroll
        for (int mt = 0; mt < 5; ++mt) {
            s16x8 a = {0, 0, 0, 0, 0, 0, 0, 0};
            int ch = chs[mt];
            if (quad == 0 && ch >= 0) {
                #pragma unroll
                for (int j = 0; j < 5; ++j) a[j] = (short)f2bf(W1[ch * 5 + j]);
                a[5] = (short)f2bf(b1[ch]);   // bias slot; B supplies 1.0 at k=5
            }
            aW1[mt] = a;
        }
    }

    // ---------- init 0c: epilogue constants (b2 folded into GEMM; only W3 left) ----------
    float w3v[NT][4];
    #pragma unroll
    for (int nt = 0; nt < NT; ++nt)
        #pragma unroll
        for (int r = 0; r < 4; ++r) {
            int o = nt * 16 + quad * 4 + r;
            w3v[nt][r] = (o < 37) ? W3[o] : 0.f;
        }
    const float b3v = b3[0];
    float cf[18];
    #pragma unroll
    for (int i = 0; i < 18; ++i) cf[i] = coeff[i];

    // ---------- helpers ----------
    auto prestage_u = [&](int grp) {   // stage u halo for group grp into u_sbuf[grp&1]
        for (int idx = t; idx < TB * USTRIDE; idx += 256) {
            int b = idx / USTRIDE, k = idx - b * USTRIDE;
            int gi = k + 36; gi -= (gi >= 40) ? 40 : 0; gi -= (gi >= 40) ? 40 : 0;
            u_sbuf[grp & 1][idx] = u[(size_t)(b0_block + grp * TB + b) * 40 + gi];
        }
    };

    auto poly = [&](int grp) {         // polynomial term for this wave's output rows
        const float* u_s = u_sbuf[grp & 1];
        float* o1 = out1_sb[grp & 1];
        #pragma unroll
        for (int pass = 0; pass < 2; ++pass) {
            int i = pass ? 4 : quad;
            bool act = pass ? (quad == 0) : true;
            if (act) {
                int m = (wave + 4 * i) * 16 + l15;
                int p = m >> 3, b = m & 7;
                const float* us = &u_s[b * USTRIDE + p];
                float um2 = us[2], um1 = us[3], u0 = us[4], up1 = us[5], up2 = us[6];
                float r = cf[0] + cf[1]*um2 + cf[2]*um1 + cf[3]*u0 + cf[4]*up1 + cf[5]*up2
                        + cf[6]*um2*um2 + cf[7]*um1*um1 + cf[8]*u0*u0 + cf[9]*up1*up1 + cf[10]*up2*up2
                        + cf[11]*um2*um1 + cf[12]*um1*u0 + cf[13]*u0*up1 + cf[14]*up1*up2
                        + cf[15]*um2*u0 + cf[16]*um1*up1 + cf[17]*u0*up2;
                o1[m] = r;
            }
        }
    };

    auto phase2 = [&](int grp) {       // conv1 via MFMA + GLU -> gtile[grp&1]
        const float* u_s = u_sbuf[grp & 1];
        unsigned short* gt = &gtile[grp & 1][0];
        #pragma unroll
        for (int i = 0; i < 6; ++i) {
            const int ct  = wave + 4 * i;              // 24 col-tiles (368 live cols)
            const int col = ct * 16 + l15;
            const int b = col & 7, h = col >> 3;
            const int hc = (h < HALO) ? h : 0;
            s16x8 bU = {0, 0, 0, 0, 0, 0, 0, 0};
            if (quad == 0) {
                const float* us = &u_s[b * USTRIDE + hc];   // taps u[(h-4+j)%40], j=0..4
                union { s16x8 v; unsigned int w[4]; } bu;
                bu.w[0] = pk_bf16(us[0], us[1]);
                bu.w[1] = pk_bf16(us[2], us[3]);
                bu.w[2] = pk_bf16(us[4], 1.0f);            // 1.0 -> bias slot k=5
                bu.w[3] = 0;
                bU = bu.v;
            }
            f32x4 a0 = {0.f,0.f,0.f,0.f}, a1 = a0, a2 = a0, a3 = a0, a4 = a0;
            a0 = __builtin_amdgcn_mfma_f32_16x16x32_bf16(aW1[0], bU, a0, 0, 0, 0);
            a1 = __builtin_amdgcn_mfma_f32_16x16x32_bf16(aW1[1], bU, a1, 0, 0, 0);
            a2 = __builtin_amdgcn_mfma_f32_16x16x32_bf16(aW1[2], bU, a2, 0, 0, 0);
            a3 = __builtin_amdgcn_mfma_f32_16x16x32_bf16(aW1[3], bU, a3, 0, 0, 0);
            a4 = __builtin_amdgcn_mfma_f32_16x16x32_bf16(aW1[4], bU, a4, 0, 0, 0);
            if (h < HALO) {
                float v0[4], v1[4], v2[4];
                #pragma unroll
                for (int r = 0; r < 4; ++r) {
                    v0[r] = fmaxf(a0[r], 0.f);
                    v1[r] = fmaxf(a1[r], 0.f);
                    if (quad >= 2) v1[r] *= fmaxf(a3[r], 0.f);          // ch24-31 gate
                    v2[r] = fmaxf(a2[r], 0.f) * fmaxf(a4[r], 0.f);      // ch32-47 gate
                }
                union { s16x4 v; unsigned int w[2]; } w0, w1, w2;
                w0.w[0] = pk_bf16(v0[0], v0[1]); w0.w[1] = pk_bf16(v0[2], v0[3]);
                w1.w[0] = pk_bf16(v1[0], v1[1]); w1.w[1] = pk_bf16(v1[2], v1[3]);
                w2.w[0] = pk_bf16(v2[0], v2[1]); w2.w[1] = pk_bf16(v2[2], v2[3]);
                unsigned short* gp = &gt[b * GSTRIDE + h * 48 + quad * 4];
                *(s16x4*)(gp)      = w0.v;
                *(s16x4*)(gp + 16) = w1.v;
                *(s16x4*)(gp + 32) = w2.v;
            }
        }
    };

    // ---------- prologue ----------
    prestage_u(0);
    __syncthreads();   // B1: B_lds + u_sbuf[0] ready

    // stage-2 A-fragments (W2 + b2 row), all 3 N-tiles per wave -> 3 independent MFMA chains
    s16x8 aW2[NT][8];
    #pragma unroll
    for (int nt = 0; nt < NT; ++nt)
        #pragma unroll
        for (int ks = 0; ks < 8; ++ks)
            aW2[nt][ks] = *(const s16x8*)&B_lds[((nt * 8 + ks) * 64 + lane) * 8];

    poly(0);
    prestage_u(1);
    __syncthreads();   // B2: aW2 fragment reads done -> safe to overwrite gtile[0]

    phase2(0);
    __syncthreads();   // B3: gtile[0] + out1_sb[0] ready

    // ---------- main loop: one barrier per window; P3(g) || P2(g+1) on opposite buffers ----------
    for (int g = 0; g < NBG; ++g) {
        const int b0 = b0_block + g * TB;
        const unsigned short* gt = &gtile[g & 1][0];
        const float* o1 = out1_sb[g & 1];

        // phase 3: each wave: 5 M-tiles x all 3 N-tiles (3 indep chains, shared bg)
        #pragma unroll
        for (int i = 0; i < 5; ++i) {
            const int mt = wave + 4 * i;               // 20 M-tiles (320 G-rows)
            const int m  = mt * 16 + l15;
            const int p  = m >> 3, b = m & 7;
            const unsigned short* gbase = &gt[b * GSTRIDE + p * 48 + quad * 8];
            s16x8 bg[8];
            #pragma unroll
            for (int ks = 0; ks < 8; ++ks) bg[ks] = *(const s16x8*)(gbase + ks * 32);
            {   // bias row: B[k=240][*] must be 1.0 (k=240 <-> ks=7, quad=2, j=0)
                s16x8 b7 = bg[7];
                if (quad == 2) b7[0] = (short)0x3F80;
                bg[7] = b7;
            }
            f32x4 c0 = {0.f,0.f,0.f,0.f}, c1 = c0, c2 = c0;
            #pragma unroll
            for (int ks = 0; ks < 8; ++ks) {
                c0 = __builtin_amdgcn_mfma_f32_16x16x32_bf16(aW2[0][ks], bg[ks], c0, 0, 0, 0);
                c1 = __builtin_amdgcn_mfma_f32_16x16x32_bf16(aW2[1][ks], bg[ks], c1, 0, 0, 0);
                c2 = __builtin_amdgcn_mfma_f32_16x16x32_bf16(aW2[2][ks], bg[ks], c2, 0, 0, 0);
            }
            // epilogue: c already includes b2; sum relu(h2)*W3 over channels, 2 shuffles
            float s = 0.f;
            #pragma unroll
            for (int r = 0; r < 4; ++r) {
                s += fmaxf(c0[r], 0.f) * w3v[0][r];
                s += fmaxf(c1[r], 0.f) * w3v[1][r];
                s += fmaxf(c2[r], 0.f) * w3v[2][r];
            }
            s += __shfl_xor(s, 16, 64);                // sum the 4 quads
            s += __shfl_xor(s, 32, 64);
            if (lane < 16) {
                int mo = mt * 16 + lane;
                out[(size_t)(b0 + (mo & 7)) * 40 + (mo >> 3)] = s + b3v + o1[mo];
            }
        }

        if (g + 1 < NBG) {
            poly(g + 1);                 // writes out1_sb[(g+1)&1]
            phase2(g + 1);               // writes gtile[(g+1)&1] (opposite buffer of P3 above)
            if (g + 2 < NBG) prestage_u(g + 2);
            __syncthreads();             // window barrier: gtile[(g+1)&1] + out1_sb[(g+1)&1] ready
        }
    }
}

extern "C" void kernel_launch(void* const* d_in, const int* in_sizes, int n_in,
                              void* d_out, int out_size, void* d_ws, size_t ws_size,
                              hipStream_t stream) {
    // inputs: 0=t(unused), 1=u, 2=coeff, 3=W1, 4=b1, 5=W2, 6=b2, 7=W3, 8=b3
    const float* u     = (const float*)d_in[1];
    const float* coeff = (const float*)d_in[2];
    const float* W1    = (const float*)d_in[3];
    const float* b1    = (const float*)d_in[4];
    const float* W2    = (const float*)d_in[5];
    const float* b2    = (const float*)d_in[6];
    const float* W3    = (const float*)d_in[7];
    const float* b3    = (const float*)d_in[8];
    float* out = (float*)d_out;

    const int n_batch = in_sizes[1] / 40;            // 65536
    const int grid = n_batch / (TB * NBG);           // 1024 blocks
    lorenz96_fused<<<grid, 256, 0, stream>>>(u, coeff, W1, b1, W2, b2, W3, b3, out);
}